// Round 12
// baseline (685.935 us; speedup 1.0000x reference)
//
#include <hip/hip_runtime.h>

typedef unsigned short u16;
typedef unsigned int u32;
typedef unsigned long long u64;
typedef __attribute__((ext_vector_type(8))) short s16x8;
typedef __attribute__((ext_vector_type(4))) float f32x4;

#define MFMA16(a, b, c) __builtin_amdgcn_mfma_f32_16x16x32_bf16((a), (b), (c), 0, 0, 0)

static constexpr int Bn = 512, Tn = 128, Dn = 128, Hn = 256;
static constexpr int NG = 4 * Hn;           // 1024 gate rows
static constexpr int KG = 2 * Dn + Hn;      // 512 gate K (c_c | m | h)
static constexpr long long BTD = (long long)Bn * Tn * Dn;

__device__ __forceinline__ u16 f2bf(float f) {
  union { float f; unsigned u; } v; v.f = f;
  unsigned u = v.u;
  return (u16)((u + 0x7fffu + ((u >> 16) & 1u)) >> 16);
}
__device__ __forceinline__ float bf2f(u16 h) {
  union { unsigned u; float f; } v; v.u = ((unsigned)h) << 16;
  return v.f;
}
// fast activations: v_exp_f32 + v_rcp_f32 (|err| ~1e-6, threshold 5.9e-2)
__device__ __forceinline__ float sigm(float x) {
  return __builtin_amdgcn_rcpf(1.f + __expf(-x));
}
__device__ __forceinline__ float ftanh(float x) {
  return 1.f - 2.f * __builtin_amdgcn_rcpf(1.f + __expf(2.f * x));
}

// ---------------- K0: fused weight prepack + delta/gamma_x/m/x pack (round-10) ----------------
// blocks [0,2048):    weight prepack to bf16
// blocks [2048,2304): delta scan, per-(b,d) threads (65536, full-chip TLP)
__global__ void k_prep(const float* __restrict__ W_ih, const float* __restrict__ W_hh,
                       const float* __restrict__ W_hr, const float* __restrict__ W_fr,
                       const float* __restrict__ W_dh, const float* __restrict__ W_wc,
                       const float* __restrict__ x, const int* __restrict__ mask,
                       const float* __restrict__ W_dx, const float* __restrict__ b_dx,
                       u16* Wg, u16* Whr_b, u16* Wfr_b, u16* Wdh_b, u16* Wwc_b,
                       u16* delta_bf, u16* gx_bf, u16* m_bf, u16* x_bf) {
  if (blockIdx.x < 2048) {
    int i = blockIdx.x * 256 + threadIdx.x;   // up to 524288
    if (i < NG * KG) {
      int n = i >> 9, k = i & 511;
      float v = (k < 256) ? W_ih[n * 256 + k] : W_hh[n * 256 + (k - 256)];
      Wg[i] = f2bf(v);
    }
    if (i < Dn * Hn) Whr_b[i] = f2bf(W_hr[i]);                    // [128][256]
    if (i < Dn * Dn) {                                            // [128][128], zero diag
      int r = i >> 7, c = i & 127;
      Wfr_b[i] = f2bf(r == c ? 0.f : W_fr[i]);
    }
    if (i < Hn * Dn) Wdh_b[i] = f2bf(W_dh[i]);                    // [256][128]
    if (i < Dn * Hn) Wwc_b[i] = f2bf(W_wc[i]);                    // [128][256]
    return;
  }
  // delta part: 256 blocks x 256 threads = 65536 = B * D (one thread per (b,d))
  int idx = (blockIdx.x - 2048) * 256 + threadIdx.x;
  int b = idx >> 7, d = idx & 127;
  float dxd = W_dx[d * Dn + d], bxd = b_dx[d];
  float del = 0.f;
  const float* xrow = x + (long long)b * Tn * Dn + d;
  const int* mrow = mask + (long long)b * Tn * Dn + d;
  for (int t0 = 0; t0 < Tn; t0 += 4) {
    float xv[4]; int mv[4];
#pragma unroll
    for (int k = 0; k < 4; ++k) {            // 8 independent loads in flight
      xv[k] = xrow[(t0 + k) * Dn];
      mv[k] = mrow[(t0 + k) * Dn];
    }
#pragma unroll
    for (int k = 0; k < 4; ++k) {
      int t = t0 + k;
      long long o = ((long long)t * Bn + b) * Dn + d;
      delta_bf[o] = f2bf(del);                                     // exact (integer <= 128)
      gx_bf[o] = f2bf(__expf(-fmaxf(del * dxd + bxd, 0.f)));
      float m = (float)mv[k];
      m_bf[o] = f2bf(m);
      x_bf[o] = f2bf(xv[k]);
      del = m + (1.f - m) * (del + 1.f);                           // delta[t+1] from m[t]
    }
  }
}

// ---------------- K2: gamma_h only (alpha folded into k_main) ----------------
__global__ void k_ga(const u16* __restrict__ delta_bf, const u16* __restrict__ Wdh_b,
                     const float* __restrict__ b_dh, u16* __restrict__ gammah) {
  int tid = threadIdx.x, wid = tid >> 6, l = tid & 63;
  int lr = l & 15, lg = l >> 4;
  int bid = blockIdx.x;                 // 4096
  int t = bid >> 5, b0 = (bid & 31) << 4;
  const u16* Arow = delta_bf + ((long long)t * Bn + b0) * Dn;
  s16x8 afr[4];
#pragma unroll
  for (int ks = 0; ks < 4; ++ks)
    afr[ks] = *(const s16x8*)(Arow + (long long)lr * Dn + ks * 32 + lg * 8);
#pragma unroll
  for (int q = 0; q < 4; ++q) {
    int n0 = (wid * 4 + q) * 16;
    f32x4 acc = {0.f, 0.f, 0.f, 0.f};
#pragma unroll
    for (int ks = 0; ks < 4; ++ks) {
      s16x8 bfr = *(const s16x8*)(Wdh_b + (long long)(n0 + lr) * Dn + ks * 32 + lg * 8);
      acc = MFMA16(afr[ks], bfr, acc);
    }
    int n = n0 + lr;
    float bb = b_dh[n];
#pragma unroll
    for (int r = 0; r < 4; ++r) {
      int row = lg * 4 + r;
      float g = __expf(-fmaxf(acc[r] + bb, 0.f));
      gammah[((long long)t * Bn + b0 + row) * Hn + n] = f2bf(g);
    }
  }
}

// ---------------- K4: cooperative, weight-stationary, N-split scan ----------------
// Round-10 winner + IN-KERNEL ALPHA: wave wid computes its own 16-col alpha
// tile via 8 MFMAs over [gx|m] rows (K=256). MFMA C-layout for n-tile
// [16*wid,+16) is (row=lg*4+r, col=wid*16+lr) == exactly the (row,dd) the
// phase-2 consumer uses -> alpha lives entirely in registers, never in memory.
__global__ __launch_bounds__(512) void k_main(
    const u16* __restrict__ x_bf, const u16* __restrict__ m_bf,
    const u16* __restrict__ gx_bf,
    const u16* __restrict__ Wg, const u16* __restrict__ Whr_b, const u16* __restrict__ Wfr_b,
    const u16* __restrict__ Wwc_b, const float* __restrict__ b_wc,
    const u16* __restrict__ gammah,
    const float* __restrict__ b_ih, const float* __restrict__ b_hh,
    const float* __restrict__ b_hr, const float* __restrict__ b_fr,
    float* __restrict__ out, u64* __restrict__ Hex, int* __restrict__ flags) {
  __shared__ __align__(16) u16 A_lds[64 * 128];   // c_c(0..15) | m(16..31) | h_dec(32..63)
  __shared__ __align__(16) u16 Axc[16 * 128];     // x_c, K=128
  __shared__ __align__(16) float G_lds[16 * 128]; // gates [row][col]

  const int tid = threadIdx.x, wid = tid >> 6, l = tid & 63;
  const int lr = l & 15, lg = l >> 4;
  const int g = blockIdx.x & 31, s = blockIdx.x >> 5;
  const int b0 = g * 16;

  // zero h_dec region (h0 = 0)
  for (int i = tid; i < 32 * 128; i += 512) A_lds[32 * 128 + i] = 0;

  // ---- per-wave d-tile (phases 1-2) ----
  const int dd = wid * 16 + lr;
  const float bhr = b_hr[dd], bfr = b_fr[dd], bwc = b_wc[dd];

  // ---- pointwise mapping: thread = (prow, pjj) ----
  const int prow = tid >> 5, pjj = tid & 31;
  const int pj = 32 * s + pjj;
  const float bg0 = b_ih[0 * 256 + pj] + b_hh[0 * 256 + pj];
  const float bg1 = b_ih[1 * 256 + pj] + b_hh[1 * 256 + pj];
  const float bg2 = b_ih[2 * 256 + pj] + b_hh[2 * 256 + pj];
  const float bg3 = b_ih[3 * 256 + pj] + b_hh[3 * 256 + pj];

  // ---- register-resident weight fragments ----
  s16x8 whr[8], wfr[4], wwc[8], wg[16];
#pragma unroll
  for (int ks = 0; ks < 8; ++ks)
    whr[ks] = *(const s16x8*)(Whr_b + (long long)dd * Hn + ks * 32 + lg * 8);
#pragma unroll
  for (int ks = 0; ks < 4; ++ks)
    wfr[ks] = *(const s16x8*)(Wfr_b + (long long)dd * Dn + ks * 32 + lg * 8);
#pragma unroll
  for (int ks = 0; ks < 8; ++ks)       // W_wc row = dd (n-tile = wave's d-tile)
    wwc[ks] = *(const s16x8*)(Wwc_b + (long long)dd * (2 * Dn) + ks * 32 + lg * 8);
  {
    const int q = wid >> 1;
    const long long grow = q * 256 + 32 * s + 16 * (wid & 1) + lr;  // global gate row
#pragma unroll
    for (int ks = 0; ks < 16; ++ks)
      wg[ks] = *(const s16x8*)(Wg + grow * KG + ks * 32 + lg * 8);
  }

  const u16* a_base = A_lds + lg * 128 + lr * 8;
  const u16* axc_base = Axc + lg * 128 + lr * 8;

  float cst = 0.f;                                  // cell state: 1 per thread
  float xn[4], mnv[4];                              // scalar prefetch regs (t)
  s16x8 afrA[8];                                    // alpha A-fragments [gx|m] (t)
#pragma unroll
  for (int r = 0; r < 4; ++r) {
    int row = lg * 4 + r;
    long long o = ((long long)0 * Bn + b0 + row) * Dn + dd;
    xn[r] = bf2f(x_bf[o]); mnv[r] = bf2f(m_bf[o]);
  }
#pragma unroll
  for (int ks = 0; ks < 8; ++ks) {
    const u16* src = (ks < 4) ? gx_bf : m_bf;
    afrA[ks] = *(const s16x8*)(src + ((long long)0 * Bn + b0 + lr) * Dn
                               + (ks & 3) * 32 + lg * 8);
  }

  float* out0 = out;
  float* out1 = out + BTD;
  float* out2 = out + 2 * BTD;
  float* out3 = out + 3 * BTD;

#pragma unroll 1
  for (int t = 0; t < Tn; ++t) {
    __syncthreads();  // h_dec(t) in LDS visible
    // gammah(t+1) prefetch for this step's pointwise
    float gmh = 1.f;
    if (t + 1 < Tn)
      gmh = bf2f(gammah[((long long)(t + 1) * Bn + b0 + prow) * Hn + pj]);

    // ---- phase 1: x_h = h_dec @ W_hr^T + b_hr  AND  alpha(t) (reg-only GEMM) ----
    f32x4 acc = {0.f, 0.f, 0.f, 0.f};
    f32x4 aacc = {0.f, 0.f, 0.f, 0.f};
#pragma unroll
    for (int ks = 0; ks < 8; ++ks) {
      s16x8 a = *(const s16x8*)(a_base + 32 * 128 + ks * 512);
      acc = MFMA16(a, whr[ks], acc);
      aacc = MFMA16(afrA[ks], wwc[ks], aacc);      // alpha: [gx|m] @ W_wc^T
    }
    float xh[4], xv[4], av[4], mv[4];
#pragma unroll
    for (int r = 0; r < 4; ++r) {
      int row = lg * 4 + r;
      xh[r] = acc[r] + bhr;
      xv[r] = xn[r]; mv[r] = mnv[r]; av[r] = aacc[r] + bwc;
      float xc = (mv[r] > 0.5f) ? xv[r] : xh[r];
      Axc[(dd >> 3) * 128 + row * 8 + (dd & 7)] = f2bf(xc);
      A_lds[(16 + (dd >> 3)) * 128 + row * 8 + (dd & 7)] = f2bf(mv[r]);
    }
    __syncthreads();  // x_c, m ready

    // ---- phase 2: z_h = x_c @ W_fr'^T + b_fr ----
    acc = f32x4{0.f, 0.f, 0.f, 0.f};
#pragma unroll
    for (int ks = 0; ks < 4; ++ks) {
      s16x8 a = *(const s16x8*)(axc_base + ks * 512);
      acc = MFMA16(a, wfr[ks], acc);
    }
    float zv[4], chv[4];
#pragma unroll
    for (int r = 0; r < 4; ++r) {
      int row = lg * 4 + r;
      zv[r] = acc[r] + bfr;
      chv[r] = av[r] * zv[r] + (1.f - av[r]) * xh[r];
      float ccv = (mv[r] > 0.5f) ? xv[r] : chv[r];
      A_lds[(dd >> 3) * 128 + row * 8 + (dd & 7)] = f2bf(ccv);
    }
    __syncthreads();  // full A (c_c | m | h_dec) ready

    // ---- phase 3: gates GEMM + t+1 prefetch (scalars + alpha fragments) ----
    if (t + 1 < Tn) {
#pragma unroll
      for (int r = 0; r < 4; ++r) {
        int row = lg * 4 + r;
        long long o = ((long long)(t + 1) * Bn + b0 + row) * Dn + dd;
        xn[r] = bf2f(x_bf[o]); mnv[r] = bf2f(m_bf[o]);
      }
#pragma unroll
      for (int ks = 0; ks < 8; ++ks) {
        const u16* src = (ks < 4) ? gx_bf : m_bf;
        afrA[ks] = *(const s16x8*)(src + ((long long)(t + 1) * Bn + b0 + lr) * Dn
                                   + (ks & 3) * 32 + lg * 8);
      }
    }
    acc = f32x4{0.f, 0.f, 0.f, 0.f};
#pragma unroll
    for (int ks = 0; ks < 16; ++ks) {
      s16x8 a = *(const s16x8*)(a_base + ks * 512);
      acc = MFMA16(a, wg[ks], acc);
    }
#pragma unroll
    for (int r = 0; r < 4; ++r)
      G_lds[(lg * 4 + r) * 128 + wid * 16 + lr] = acc[r];
    __syncthreads();  // gates ready; all A_lds reads of step t done

    // ---- pointwise LSTM: thread = (prow, pjj) ----
    float gi = G_lds[prow * 128 + 0 * 32 + pjj] + bg0;
    float gf = G_lds[prow * 128 + 1 * 32 + pjj] + bg1;
    float gg = G_lds[prow * 128 + 2 * 32 + pjj] + bg2;
    float go = G_lds[prow * 128 + 3 * 32 + pjj] + bg3;
    float iv = sigm(gi), fv = sigm(gf), gv = ftanh(gg), ov = sigm(go);
    cst = fv * cst + iv * gv;
    float h = ov * ftanh(cst);

    if (t + 1 < Tn) {
      // ---- export of h_dec(t+1) slice + OWN-slice direct LDS write ----
      unsigned hv = (unsigned)f2bf(h * gmh);
      unsigned up = (unsigned)__shfl_xor((int)hv, 1);
      u32* HexW = (u32*)(Hex + (size_t)((t + 1) & 1) * 32768 + (size_t)g * 1024);
      if (!(tid & 1))
        __hip_atomic_store(HexW + (prow * 128 + 16 * s + (pjj >> 1)), hv | (up << 16),
                           __ATOMIC_RELAXED, __HIP_MEMORY_SCOPE_AGENT);
      A_lds[(32 + (pj >> 3)) * 128 + prow * 8 + (pj & 7)] = (u16)hv;  // own slice
      __syncthreads();  // every wave drains vmcnt(0): Hex data ACK'd at IC
      if (tid == 0)
        __hip_atomic_store(flags + (((g << 3) | s) << 5), t + 1,
                           __ATOMIC_RELAXED, __HIP_MEMORY_SCOPE_AGENT);
    }

    // ---- output stores (wave s; overlaps peers' polls) ----
    if (wid == s) {
#pragma unroll
      for (int r = 0; r < 4; ++r) {
        int row = lg * 4 + r;
        long long gx = ((long long)(b0 + row) * Tn + t) * Dn + dd;
        out0[gx] = xh[r];
        out1[gx] = zv[r];
        out2[gx] = chv[r];
        out3[gx] = chv[r];
      }
    }

    if (t + 1 < Tn && wid != s) {
      // ---- wave w polls ONLY flag[w] (uniform addr), reads back slice w ----
      const int target = t + 1;
      const int* fp = flags + (((g << 3) | wid) << 5);
      int v;
      do {
        v = __hip_atomic_load(fp, __ATOMIC_RELAXED, __HIP_MEMORY_SCOPE_AGENT);
      } while (v < target);
      const int row = l & 15, c = 4 * wid + (l >> 4);   // c in [4w, 4w+4)
      const u64* rp = Hex + (size_t)((t + 1) & 1) * 32768 + (size_t)g * 1024
                      + (row * 64 + c * 2);
      u64 w0 = __hip_atomic_load(rp, __ATOMIC_RELAXED, __HIP_MEMORY_SCOPE_AGENT);
      u64 w1 = __hip_atomic_load(rp + 1, __ATOMIC_RELAXED, __HIP_MEMORY_SCOPE_AGENT);
      u64* dst = (u64*)(A_lds + (32 + c) * 128 + row * 8);
      dst[0] = w0; dst[1] = w1;
      // loop-top barrier publishes h_dec(t+1)
    }
  }
}

extern "C" void kernel_launch(void* const* d_in, const int* in_sizes, int n_in,
                              void* d_out, int out_size, void* d_ws, size_t ws_size,
                              hipStream_t stream) {
  (void)in_sizes; (void)n_in; (void)out_size; (void)ws_size;
  const float* x = (const float*)d_in[0];
  const int* mask = (const int*)d_in[1];
  const float* W_ih = (const float*)d_in[2];
  const float* W_hh = (const float*)d_in[3];
  const float* b_ih = (const float*)d_in[4];
  const float* b_hh = (const float*)d_in[5];
  const float* W_dh = (const float*)d_in[6];
  const float* b_dh = (const float*)d_in[7];
  const float* W_dx = (const float*)d_in[8];
  const float* b_dx = (const float*)d_in[9];
  const float* W_hr = (const float*)d_in[10];
  const float* b_hr = (const float*)d_in[11];
  const float* W_fr = (const float*)d_in[12];
  const float* b_fr = (const float*)d_in[13];
  const float* W_wc = (const float*)d_in[14];
  const float* b_wc = (const float*)d_in[15];

  char* ws = (char*)d_ws;
  size_t off = 0;
  auto alloc = [&](size_t bytes) {
    void* p = ws + off;
    off = (off + bytes + 255) & ~(size_t)255;
    return p;
  };
  const long long TBD = (long long)Tn * Bn * Dn;      // 8.4M
  const long long TBH = (long long)Tn * Bn * Hn;      // 16.8M
  u16* delta_bf = (u16*)alloc(TBD * 2);
  u16* gx_bf    = (u16*)alloc(TBD * 2);
  u16* m_bf     = (u16*)alloc(TBD * 2);
  u16* x_bf     = (u16*)alloc(TBD * 2);
  u16* gammah   = (u16*)alloc(TBH * 2);
  u16* Wg    = (u16*)alloc((size_t)NG * KG * 2);
  u16* Whr_b = (u16*)alloc((size_t)Dn * Hn * 2);
  u16* Wfr_b = (u16*)alloc((size_t)Dn * Dn * 2);
  u16* Wdh_b = (u16*)alloc((size_t)Hn * Dn * 2);
  u16* Wwc_b = (u16*)alloc((size_t)Dn * Hn * 2);

  // Hex (512 KB) + flags (32 KB: 256 x 128B lines) ALIAS delta_bf's region:
  // k_ga (the only delta_bf reader) completes before k_main starts (stream
  // order), and k_prep rewrites delta_bf every call -> deterministic.
  u64* Hex = (u64*)delta_bf;                               // 2*32*1024 u64 = 512 KB
  int* flags = (int*)((char*)delta_bf + 512 * 1024);       // 256 * 128 B

  k_prep<<<2304, 256, 0, stream>>>(W_ih, W_hh, W_hr, W_fr, W_dh, W_wc,
                                   x, mask, W_dx, b_dx,
                                   Wg, Whr_b, Wfr_b, Wdh_b, Wwc_b,
                                   delta_bf, gx_bf, m_bf, x_bf);
  k_ga<<<4096, 256, 0, stream>>>(delta_bf, Wdh_b, b_dh, gammah);
  hipMemsetAsync(flags, 0, 256 * 128, stream);             // zero block-flags each launch

  void* args[] = {
    (void*)&x_bf, (void*)&m_bf, (void*)&gx_bf, (void*)&Wg, (void*)&Whr_b,
    (void*)&Wfr_b, (void*)&Wwc_b, (void*)&b_wc, (void*)&gammah,
    (void*)&b_ih, (void*)&b_hh, (void*)&b_hr, (void*)&b_fr,
    (void*)&d_out, (void*)&Hex, (void*)&flags
  };
  hipLaunchCooperativeKernel((const void*)k_main, dim3(256), dim3(512), args, 0, stream);
}

// Round 13
// 540.520 us; speedup vs baseline: 1.2690x; 1.2690x over previous
//
#include <hip/hip_runtime.h>

typedef unsigned short u16;
typedef unsigned int u32;
typedef unsigned long long u64;
typedef __attribute__((ext_vector_type(8))) short s16x8;
typedef __attribute__((ext_vector_type(4))) float f32x4;

#define MFMA16(a, b, c) __builtin_amdgcn_mfma_f32_16x16x32_bf16((a), (b), (c), 0, 0, 0)

static constexpr int Bn = 512, Tn = 128, Dn = 128, Hn = 256;
static constexpr int NG = 4 * Hn;           // 1024 gate rows
static constexpr int KG = 2 * Dn + Hn;      // 512 gate K (c_c | m | h)
static constexpr long long BTD = (long long)Bn * Tn * Dn;

__device__ __forceinline__ u16 f2bf(float f) {
  union { float f; unsigned u; } v; v.f = f;
  unsigned u = v.u;
  return (u16)((u + 0x7fffu + ((u >> 16) & 1u)) >> 16);
}
__device__ __forceinline__ float bf2f(u16 h) {
  union { unsigned u; float f; } v; v.u = ((unsigned)h) << 16;
  return v.f;
}
// fast activations: v_exp_f32 + v_rcp_f32 (|err| ~1e-6, threshold 5.9e-2)
__device__ __forceinline__ float sigm(float x) {
  return __builtin_amdgcn_rcpf(1.f + __expf(-x));
}
__device__ __forceinline__ float ftanh(float x) {
  return 1.f - 2.f * __builtin_amdgcn_rcpf(1.f + __expf(2.f * x));
}

// ---------------- K0: weight prepack to bf16 (separate launch: measured
// ~40us faster than fusing with the delta scan -- rounds 6 vs 9/10) --------
__global__ void k_pack(const float* __restrict__ W_ih, const float* __restrict__ W_hh,
                       const float* __restrict__ W_hr, const float* __restrict__ W_fr,
                       const float* __restrict__ W_dh, const float* __restrict__ W_wc,
                       u16* Wg, u16* Whr_b, u16* Wfr_b, u16* Wdh_b, u16* Wwc_b) {
  int i = blockIdx.x * 256 + threadIdx.x;   // up to 524288
  if (i < NG * KG) {
    int n = i >> 9, k = i & 511;
    float v = (k < 256) ? W_ih[n * 256 + k] : W_hh[n * 256 + (k - 256)];
    Wg[i] = f2bf(v);
  }
  if (i < Dn * Hn) Whr_b[i] = f2bf(W_hr[i]);                      // [128][256]
  if (i < Dn * Dn) {                                              // [128][128], zero diag
    int r = i >> 7, c = i & 127;
    Wfr_b[i] = f2bf(r == c ? 0.f : W_fr[i]);
  }
  if (i < Hn * Dn) Wdh_b[i] = f2bf(W_dh[i]);                      // [256][128]
  if (i < Dn * Hn) Wwc_b[i] = f2bf(W_wc[i]);                      // [128][256]
}

// ---------------- K1: deltas + gamma_x + m + x (time-major bf16), unroll x4 ----------------
__global__ void k_delta(const float* __restrict__ x, const int* __restrict__ mask,
                        const float* __restrict__ W_dx, const float* __restrict__ b_dx,
                        u16* delta_bf, u16* gx_bf, u16* m_bf, u16* x_bf) {
  int idx = blockIdx.x * 256 + threadIdx.x;  // B*D = 65536 threads
  int b = idx >> 7, d = idx & 127;
  float dxd = W_dx[d * Dn + d], bxd = b_dx[d];
  float del = 0.f;
  const float* xrow = x + (long long)b * Tn * Dn + d;
  const int* mrow = mask + (long long)b * Tn * Dn + d;
  for (int t0 = 0; t0 < Tn; t0 += 4) {
    float xv[4]; int mv[4];
#pragma unroll
    for (int k = 0; k < 4; ++k) {            // 8 independent loads in flight
      xv[k] = xrow[(t0 + k) * Dn];
      mv[k] = mrow[(t0 + k) * Dn];
    }
#pragma unroll
    for (int k = 0; k < 4; ++k) {
      int t = t0 + k;
      long long o = ((long long)t * Bn + b) * Dn + d;
      delta_bf[o] = f2bf(del);                                     // exact (integer <= 128)
      gx_bf[o] = f2bf(__expf(-fmaxf(del * dxd + bxd, 0.f)));
      float m = (float)mv[k];
      m_bf[o] = f2bf(m);
      x_bf[o] = f2bf(xv[k]);
      del = m + (1.f - m) * (del + 1.f);                           // delta[t+1] from m[t]
    }
  }
}

// ---------------- K2: fused gamma_h + alpha ----------------
// blocks [0,4096):   gamma_h = exp(-relu(delta @ W_dh^T + b_dh)), bf16 [T][B][H]
// blocks [4096,8192): alpha  = [gamma_x, m] @ W_wc^T + b_wc,      bf16 [T][B][D]
__global__ void k_ga(const u16* __restrict__ delta_bf, const u16* __restrict__ gx_bf,
                     const u16* __restrict__ m_bf,
                     const u16* __restrict__ Wdh_b, const u16* __restrict__ Wwc_b,
                     const float* __restrict__ b_dh, const float* __restrict__ b_wc,
                     u16* __restrict__ gammah, u16* __restrict__ alpha) {
  int tid = threadIdx.x, wid = tid >> 6, l = tid & 63;
  int lr = l & 15, lg = l >> 4;
  if (blockIdx.x < 4096) {
    int bid = blockIdx.x;
    int t = bid >> 5, b0 = (bid & 31) << 4;
    const u16* Arow = delta_bf + ((long long)t * Bn + b0) * Dn;
    s16x8 afr[4];
#pragma unroll
    for (int ks = 0; ks < 4; ++ks)
      afr[ks] = *(const s16x8*)(Arow + (long long)lr * Dn + ks * 32 + lg * 8);
#pragma unroll
    for (int q = 0; q < 4; ++q) {
      int n0 = (wid * 4 + q) * 16;
      f32x4 acc = {0.f, 0.f, 0.f, 0.f};
#pragma unroll
      for (int ks = 0; ks < 4; ++ks) {
        s16x8 bfr = *(const s16x8*)(Wdh_b + (long long)(n0 + lr) * Dn + ks * 32 + lg * 8);
        acc = MFMA16(afr[ks], bfr, acc);
      }
      int n = n0 + lr;
      float bb = b_dh[n];
#pragma unroll
      for (int r = 0; r < 4; ++r) {
        int row = lg * 4 + r;
        float g = __expf(-fmaxf(acc[r] + bb, 0.f));
        gammah[((long long)t * Bn + b0 + row) * Hn + n] = f2bf(g);
      }
    }
  } else {
    int bid = blockIdx.x - 4096;
    int t = bid >> 5, b0 = (bid & 31) << 4;
    s16x8 afr[8];
#pragma unroll
    for (int ks = 0; ks < 8; ++ks) {
      const u16* src = (ks < 4) ? gx_bf : m_bf;
      int kk = (ks & 3) * 32 + lg * 8;
      afr[ks] = *(const s16x8*)(src + ((long long)t * Bn + b0 + lr) * Dn + kk);
    }
#pragma unroll
    for (int q = 0; q < 2; ++q) {
      int n0 = (wid * 2 + q) * 16;
      f32x4 acc = {0.f, 0.f, 0.f, 0.f};
#pragma unroll
      for (int ks = 0; ks < 8; ++ks) {
        s16x8 bfr = *(const s16x8*)(Wwc_b + (long long)(n0 + lr) * (2 * Dn) + ks * 32 + lg * 8);
        acc = MFMA16(afr[ks], bfr, acc);
      }
      int n = n0 + lr;
      float bb = b_wc[n];
#pragma unroll
      for (int r = 0; r < 4; ++r)
        alpha[((long long)t * Bn + b0 + lg * 4 + r) * Dn + n] = f2bf(acc[r] + bb);
    }
  }
}

// ---------------- K4: cooperative, weight-stationary, N-split scan ----------------
// (round-10 winner, byte-identical: per-wave single-flag poll + own-slice
//  direct LDS write; RELAXED-only agent fabric, one writer per 128B line)
__global__ __launch_bounds__(512) void k_main(
    const u16* __restrict__ x_bf, const u16* __restrict__ m_bf,
    const u16* __restrict__ Wg, const u16* __restrict__ Whr_b, const u16* __restrict__ Wfr_b,
    const u16* __restrict__ gammah, const u16* __restrict__ alpha,
    const float* __restrict__ b_ih, const float* __restrict__ b_hh,
    const float* __restrict__ b_hr, const float* __restrict__ b_fr,
    float* __restrict__ out, u64* __restrict__ Hex, int* __restrict__ flags) {
  __shared__ __align__(16) u16 A_lds[64 * 128];   // c_c(0..15) | m(16..31) | h_dec(32..63)
  __shared__ __align__(16) u16 Axc[16 * 128];     // x_c, K=128
  __shared__ __align__(16) float G_lds[16 * 128]; // gates [row][col]

  const int tid = threadIdx.x, wid = tid >> 6, l = tid & 63;
  const int lr = l & 15, lg = l >> 4;
  const int g = blockIdx.x & 31, s = blockIdx.x >> 5;
  const int b0 = g * 16;

  // zero h_dec region (h0 = 0)
  for (int i = tid; i < 32 * 128; i += 512) A_lds[32 * 128 + i] = 0;

  // ---- per-wave d-tile (phases 1-2) ----
  const int dd = wid * 16 + lr;
  const float bhr = b_hr[dd], bfr = b_fr[dd];

  // ---- pointwise mapping: thread = (prow, pjj) ----
  const int prow = tid >> 5, pjj = tid & 31;
  const int pj = 32 * s + pjj;
  const float bg0 = b_ih[0 * 256 + pj] + b_hh[0 * 256 + pj];
  const float bg1 = b_ih[1 * 256 + pj] + b_hh[1 * 256 + pj];
  const float bg2 = b_ih[2 * 256 + pj] + b_hh[2 * 256 + pj];
  const float bg3 = b_ih[3 * 256 + pj] + b_hh[3 * 256 + pj];

  // ---- register-resident weight fragments ----
  s16x8 whr[8], wfr[4], wg[16];
#pragma unroll
  for (int ks = 0; ks < 8; ++ks)
    whr[ks] = *(const s16x8*)(Whr_b + (long long)dd * Hn + ks * 32 + lg * 8);
#pragma unroll
  for (int ks = 0; ks < 4; ++ks)
    wfr[ks] = *(const s16x8*)(Wfr_b + (long long)dd * Dn + ks * 32 + lg * 8);
  {
    const int q = wid >> 1;
    const long long grow = q * 256 + 32 * s + 16 * (wid & 1) + lr;  // global gate row
#pragma unroll
    for (int ks = 0; ks < 16; ++ks)
      wg[ks] = *(const s16x8*)(Wg + grow * KG + ks * 32 + lg * 8);
  }

  const u16* a_base = A_lds + lg * 128 + lr * 8;
  const u16* axc_base = Axc + lg * 128 + lr * 8;

  float cst = 0.f;                                  // cell state: 1 per thread
  float xn[4], mnv[4], an[4];                       // prefetch regs (t)
#pragma unroll
  for (int r = 0; r < 4; ++r) {
    int row = lg * 4 + r;
    long long o = ((long long)0 * Bn + b0 + row) * Dn + dd;
    xn[r] = bf2f(x_bf[o]); mnv[r] = bf2f(m_bf[o]); an[r] = bf2f(alpha[o]);
  }

  float* out0 = out;
  float* out1 = out + BTD;
  float* out2 = out + 2 * BTD;
  float* out3 = out + 3 * BTD;

#pragma unroll 1
  for (int t = 0; t < Tn; ++t) {
    __syncthreads();  // h_dec(t) in LDS visible
    // gammah(t+1) prefetch for this step's pointwise
    float gmh = 1.f;
    if (t + 1 < Tn)
      gmh = bf2f(gammah[((long long)(t + 1) * Bn + b0 + prow) * Hn + pj]);

    // ---- phase 1: x_h = h_dec @ W_hr^T + b_hr (all 8 waves, d-tile each) ----
    f32x4 acc = {0.f, 0.f, 0.f, 0.f};
#pragma unroll
    for (int ks = 0; ks < 8; ++ks) {
      s16x8 a = *(const s16x8*)(a_base + 32 * 128 + ks * 512);
      acc = MFMA16(a, whr[ks], acc);
    }
    float xh[4], xv[4], av[4], mv[4];
#pragma unroll
    for (int r = 0; r < 4; ++r) {
      int row = lg * 4 + r;
      xh[r] = acc[r] + bhr;
      xv[r] = xn[r]; mv[r] = mnv[r]; av[r] = an[r];
      float xc = (mv[r] > 0.5f) ? xv[r] : xh[r];
      Axc[(dd >> 3) * 128 + row * 8 + (dd & 7)] = f2bf(xc);
      A_lds[(16 + (dd >> 3)) * 128 + row * 8 + (dd & 7)] = f2bf(mv[r]);
    }
    __syncthreads();  // x_c, m ready

    // ---- phase 2: z_h = x_c @ W_fr'^T + b_fr ----
    acc = f32x4{0.f, 0.f, 0.f, 0.f};
#pragma unroll
    for (int ks = 0; ks < 4; ++ks) {
      s16x8 a = *(const s16x8*)(axc_base + ks * 512);
      acc = MFMA16(a, wfr[ks], acc);
    }
    float zv[4], chv[4];
#pragma unroll
    for (int r = 0; r < 4; ++r) {
      int row = lg * 4 + r;
      zv[r] = acc[r] + bfr;
      chv[r] = av[r] * zv[r] + (1.f - av[r]) * xh[r];
      float ccv = (mv[r] > 0.5f) ? xv[r] : chv[r];
      A_lds[(dd >> 3) * 128 + row * 8 + (dd & 7)] = f2bf(ccv);
    }
    __syncthreads();  // full A (c_c | m | h_dec) ready

    // ---- phase 3: gates GEMM (wave wid owns col-tile [16wid,+16)) + t+1 prefetch ----
    if (t + 1 < Tn) {
#pragma unroll
      for (int r = 0; r < 4; ++r) {
        int row = lg * 4 + r;
        long long o = ((long long)(t + 1) * Bn + b0 + row) * Dn + dd;
        xn[r] = bf2f(x_bf[o]); mnv[r] = bf2f(m_bf[o]); an[r] = bf2f(alpha[o]);
      }
    }
    acc = f32x4{0.f, 0.f, 0.f, 0.f};
#pragma unroll
    for (int ks = 0; ks < 16; ++ks) {
      s16x8 a = *(const s16x8*)(a_base + ks * 512);
      acc = MFMA16(a, wg[ks], acc);
    }
#pragma unroll
    for (int r = 0; r < 4; ++r)
      G_lds[(lg * 4 + r) * 128 + wid * 16 + lr] = acc[r];
    __syncthreads();  // gates ready; all A_lds reads of step t done

    // ---- pointwise LSTM: thread = (prow, pjj) ----
    float gi = G_lds[prow * 128 + 0 * 32 + pjj] + bg0;
    float gf = G_lds[prow * 128 + 1 * 32 + pjj] + bg1;
    float gg = G_lds[prow * 128 + 2 * 32 + pjj] + bg2;
    float go = G_lds[prow * 128 + 3 * 32 + pjj] + bg3;
    float iv = sigm(gi), fv = sigm(gf), gv = ftanh(gg), ov = sigm(go);
    cst = fv * cst + iv * gv;
    float h = ov * ftanh(cst);

    if (t + 1 < Tn) {
      // ---- export of h_dec(t+1) slice + OWN-slice direct LDS write ----
      unsigned hv = (unsigned)f2bf(h * gmh);
      unsigned up = (unsigned)__shfl_xor((int)hv, 1);
      u32* HexW = (u32*)(Hex + (size_t)((t + 1) & 1) * 32768 + (size_t)g * 1024);
      if (!(tid & 1))
        __hip_atomic_store(HexW + (prow * 128 + 16 * s + (pjj >> 1)), hv | (up << 16),
                           __ATOMIC_RELAXED, __HIP_MEMORY_SCOPE_AGENT);
      A_lds[(32 + (pj >> 3)) * 128 + prow * 8 + (pj & 7)] = (u16)hv;  // own slice, no round-trip
      __syncthreads();  // every wave drains vmcnt(0): Hex data ACK'd at IC
      if (tid == 0)
        __hip_atomic_store(flags + (((g << 3) | s) << 5), t + 1,
                           __ATOMIC_RELAXED, __HIP_MEMORY_SCOPE_AGENT);
    }

    // ---- output stores (wave s; overlaps peers' polls) ----
    if (wid == s) {
#pragma unroll
      for (int r = 0; r < 4; ++r) {
        int row = lg * 4 + r;
        long long gx = ((long long)(b0 + row) * Tn + t) * Dn + dd;
        out0[gx] = xh[r];
        out1[gx] = zv[r];
        out2[gx] = chv[r];
        out3[gx] = chv[r];
      }
    }

    if (t + 1 < Tn && wid != s) {
      // ---- wave w polls ONLY flag[w] (uniform addr), reads back slice w ----
      const int target = t + 1;
      const int* fp = flags + (((g << 3) | wid) << 5);
      int v;
      do {
        v = __hip_atomic_load(fp, __ATOMIC_RELAXED, __HIP_MEMORY_SCOPE_AGENT);
      } while (v < target);
      const int row = l & 15, c = 4 * wid + (l >> 4);   // c in [4w, 4w+4)
      const u64* rp = Hex + (size_t)((t + 1) & 1) * 32768 + (size_t)g * 1024
                      + (row * 64 + c * 2);
      u64 w0 = __hip_atomic_load(rp, __ATOMIC_RELAXED, __HIP_MEMORY_SCOPE_AGENT);
      u64 w1 = __hip_atomic_load(rp + 1, __ATOMIC_RELAXED, __HIP_MEMORY_SCOPE_AGENT);
      u64* dst = (u64*)(A_lds + (32 + c) * 128 + row * 8);
      dst[0] = w0; dst[1] = w1;
      // loop-top barrier publishes h_dec(t+1)
    }
  }
}

extern "C" void kernel_launch(void* const* d_in, const int* in_sizes, int n_in,
                              void* d_out, int out_size, void* d_ws, size_t ws_size,
                              hipStream_t stream) {
  (void)in_sizes; (void)n_in; (void)out_size; (void)ws_size;
  const float* x = (const float*)d_in[0];
  const int* mask = (const int*)d_in[1];
  const float* W_ih = (const float*)d_in[2];
  const float* W_hh = (const float*)d_in[3];
  const float* b_ih = (const float*)d_in[4];
  const float* b_hh = (const float*)d_in[5];
  const float* W_dh = (const float*)d_in[6];
  const float* b_dh = (const float*)d_in[7];
  const float* W_dx = (const float*)d_in[8];
  const float* b_dx = (const float*)d_in[9];
  const float* W_hr = (const float*)d_in[10];
  const float* b_hr = (const float*)d_in[11];
  const float* W_fr = (const float*)d_in[12];
  const float* b_fr = (const float*)d_in[13];
  const float* W_wc = (const float*)d_in[14];
  const float* b_wc = (const float*)d_in[15];

  char* ws = (char*)d_ws;
  size_t off = 0;
  auto alloc = [&](size_t bytes) {
    void* p = ws + off;
    off = (off + bytes + 255) & ~(size_t)255;
    return p;
  };
  const long long TBD = (long long)Tn * Bn * Dn;      // 8.4M
  const long long TBH = (long long)Tn * Bn * Hn;      // 16.8M
  u16* delta_bf = (u16*)alloc(TBD * 2);
  u16* gx_bf    = (u16*)alloc(TBD * 2);
  u16* m_bf     = (u16*)alloc(TBD * 2);
  u16* x_bf     = (u16*)alloc(TBD * 2);
  u16* gammah   = (u16*)alloc(TBH * 2);
  u16* alphaw   = (u16*)alloc(TBD * 2);
  u16* Wg    = (u16*)alloc((size_t)NG * KG * 2);
  u16* Whr_b = (u16*)alloc((size_t)Dn * Hn * 2);
  u16* Wfr_b = (u16*)alloc((size_t)Dn * Dn * 2);
  u16* Wdh_b = (u16*)alloc((size_t)Hn * Dn * 2);
  u16* Wwc_b = (u16*)alloc((size_t)Dn * Hn * 2);

  // Hex (512 KB) + flags (32 KB: 256 x 128B lines) ALIAS delta_bf's region:
  // k_ga (the only delta_bf reader) completes before k_main starts (stream
  // order), and k_delta rewrites delta_bf every call -> deterministic.
  u64* Hex = (u64*)delta_bf;                               // 2*32*1024 u64 = 512 KB
  int* flags = (int*)((char*)delta_bf + 512 * 1024);       // 256 * 128 B

  k_pack<<<2048, 256, 0, stream>>>(W_ih, W_hh, W_hr, W_fr, W_dh, W_wc,
                                   Wg, Whr_b, Wfr_b, Wdh_b, Wwc_b);
  k_delta<<<(Bn * Dn) / 256, 256, 0, stream>>>(x, mask, W_dx, b_dx,
                                               delta_bf, gx_bf, m_bf, x_bf);
  k_ga<<<8192, 256, 0, stream>>>(delta_bf, gx_bf, m_bf, Wdh_b, Wwc_b,
                                 b_dh, b_wc, gammah, alphaw);
  hipMemsetAsync(flags, 0, 256 * 128, stream);             // zero block-flags each launch

  void* args[] = {
    (void*)&x_bf, (void*)&m_bf, (void*)&Wg, (void*)&Whr_b, (void*)&Wfr_b,
    (void*)&gammah, (void*)&alphaw, (void*)&b_ih, (void*)&b_hh,
    (void*)&b_hr, (void*)&b_fr, (void*)&d_out, (void*)&Hex, (void*)&flags
  };
  hipLaunchCooperativeKernel((const void*)k_main, dim3(256), dim3(512), args, 0, stream);
}